// Round 2
// baseline (3846.260 us; speedup 1.0000x reference)
//
#include <hip/hip_runtime.h>

// EvenOddConvLayer: N=50000 nodes, M=20 neighbors, EVEN=ODD=64, EDGE=32, CAT=224.
// Round 2: all tensors are fp32 (per reference). Block per node, 4 waves,
// each wave processes its 5 neighbors SIMULTANEOUSLY (register tiling) so each
// weight load is reused by 5 FMAs. lane = output channel. Broadcasts via
// v_readlane (uniform k). Hoists: bc(ei,k) shared across pairs; even_i@W_pei
// computed once per node (neighbor-independent).

#define NN    50000
#define MMN   20
#define EVENC 64
#define ODDC  64
#define EDGEC 32
#define PW    5   // pairs per wave

__device__ __forceinline__ float bc(float v, int k) {
    return __uint_as_float(__builtin_amdgcn_readlane(__float_as_uint(v), k));
}
__device__ __forceinline__ float sp(float x) {            // stable softplus
    return fmaxf(x, 0.f) + log1pf(expf(-fabsf(x)));
}
__device__ __forceinline__ float sg(float x) {            // sigmoid
    return 1.f / (1.f + expf(-x));
}

__global__ __launch_bounds__(256) void eoconv_kernel(
    const float* __restrict__ even_node,
    const float* __restrict__ odd_node,
    const float* __restrict__ nbr_fea,
    const int*   __restrict__ nbr_idx,
    const float* __restrict__ W_em1, const float* __restrict__ b_em1,
    const float* __restrict__ W_eg,  const float* __restrict__ b_eg,
    const float* __restrict__ W_em2, const float* __restrict__ b_em2,
    const float* __restrict__ W_pej, const float* __restrict__ b_pej,
    const float* __restrict__ W_pei, const float* __restrict__ b_pei,
    const float* __restrict__ W_om1,
    const float* __restrict__ W_ogh, const float* __restrict__ b_ogh,
    const float* __restrict__ W_og,  const float* __restrict__ b_og,
    float* __restrict__ out)
{
    const int n    = blockIdx.x;
    const int wave = threadIdx.x >> 6;
    const int lane = threadIdx.x & 63;

    const float ei = even_node[(long)n * EVENC + lane];
    const float oi = odd_node [(long)n * ODDC  + lane];

    // ---- gather the 5 neighbors of this wave
    float ej[PW], oj[PW], nb[PW], cx[PW];
    #pragma unroll
    for (int mi = 0; mi < PW; ++mi) {
        const int  m = wave * PW + mi;
        const long p = (long)n * MMN + m;
        const int  j = nbr_idx[p];
        ej[mi] = even_node[(long)j * EVENC + lane];
        oj[mi] = odd_node [(long)j * ODDC  + lane];
        nb[mi] = (lane < EDGEC) ? nbr_fea[p * EDGEC + lane] : 0.f;
        cx[mi] = oi * oj[mi];
    }

    // ---- per-node (neighbor-independent): pei_v = even_i @ W_pei + b_pei
    float pei_v = b_pei[lane];
    #pragma unroll 4
    for (int k = 0; k < 64; ++k)
        pei_v = fmaf(bc(ei, k), W_pei[k * ODDC + lane], pei_v);

    // ---- h1 = cat @ W_em1 + b ; hg = cat @ W_ogh + b
    float h1[PW], hg[PW];
    {
        const float be1 = b_em1[lane], bgh = b_ogh[lane];
        #pragma unroll
        for (int mi = 0; mi < PW; ++mi) { h1[mi] = be1; hg[mi] = bgh; }
    }
    #pragma unroll 4
    for (int k = 0; k < 64; ++k) {               // segment 1: even_i (shared)
        const float c  = bc(ei, k);
        const float w1 = W_em1[k * EVENC + lane];
        const float wg = W_ogh[k * EVENC + lane];
        #pragma unroll
        for (int mi = 0; mi < PW; ++mi) {
            h1[mi] = fmaf(c, w1, h1[mi]);
            hg[mi] = fmaf(c, wg, hg[mi]);
        }
    }
    #pragma unroll 4
    for (int k = 0; k < 64; ++k) {               // segment 2: even_j
        const float w1 = W_em1[(64 + k) * EVENC + lane];
        const float wg = W_ogh[(64 + k) * EVENC + lane];
        #pragma unroll
        for (int mi = 0; mi < PW; ++mi) {
            const float c = bc(ej[mi], k);
            h1[mi] = fmaf(c, w1, h1[mi]);
            hg[mi] = fmaf(c, wg, hg[mi]);
        }
    }
    #pragma unroll 4
    for (int k = 0; k < 32; ++k) {               // segment 3: nbr_fea
        const float w1 = W_em1[(128 + k) * EVENC + lane];
        const float wg = W_ogh[(128 + k) * EVENC + lane];
        #pragma unroll
        for (int mi = 0; mi < PW; ++mi) {
            const float c = bc(nb[mi], k);
            h1[mi] = fmaf(c, w1, h1[mi]);
            hg[mi] = fmaf(c, wg, hg[mi]);
        }
    }
    #pragma unroll 4
    for (int k = 0; k < 64; ++k) {               // segment 4: odd_cross
        const float w1 = W_em1[(160 + k) * EVENC + lane];
        const float wg = W_ogh[(160 + k) * EVENC + lane];
        #pragma unroll
        for (int mi = 0; mi < PW; ++mi) {
            const float c = bc(cx[mi], k);
            h1[mi] = fmaf(c, w1, h1[mi]);
            hg[mi] = fmaf(c, wg, hg[mi]);
        }
    }
    float eh[PW], oh[PW];
    #pragma unroll
    for (int mi = 0; mi < PW; ++mi) { eh[mi] = sp(h1[mi]); oh[mi] = sp(hg[mi]); }

    // ---- gate/msg/odd-gate (64x64 over eh / oh)
    float g[PW], ms[PW], og[PW];
    {
        const float bg = b_eg[lane], bm = b_em2[lane], bo = b_og[lane];
        #pragma unroll
        for (int mi = 0; mi < PW; ++mi) { g[mi] = bg; ms[mi] = bm; og[mi] = bo; }
    }
    #pragma unroll 4
    for (int k = 0; k < 64; ++k) {
        const float we = W_eg [k * EVENC + lane];
        const float wm = W_em2[k * EVENC + lane];
        const float wo = W_og [k * ODDC  + lane];
        #pragma unroll
        for (int mi = 0; mi < PW; ++mi) {
            const float he = bc(eh[mi], k);
            const float ho = bc(oh[mi], k);
            g [mi] = fmaf(he, we, g [mi]);
            ms[mi] = fmaf(he, wm, ms[mi]);
            og[mi] = fmaf(ho, wo, og[mi]);
        }
    }
    float acc_e = 0.f;
    #pragma unroll
    for (int mi = 0; mi < PW; ++mi) acc_e += sg(g[mi]) * sp(ms[mi]);

    // ---- odd pair path: pej per neighbor
    float pj[PW];
    {
        const float bj = b_pej[lane];
        #pragma unroll
        for (int mi = 0; mi < PW; ++mi) pj[mi] = bj;
    }
    #pragma unroll 4
    for (int k = 0; k < 64; ++k) {
        const float wj = W_pej[k * ODDC + lane];
        #pragma unroll
        for (int mi = 0; mi < PW; ++mi)
            pj[mi] = fmaf(bc(ej[mi], k), wj, pj[mi]);
    }
    float ie[PW], ieo[PW];
    #pragma unroll
    for (int mi = 0; mi < PW; ++mi) {
        ie [mi] = oi * pj[mi];        // odd_ie
        ieo[mi] = pei_v * oj[mi];     // odd_ei
    }

    float om[PW] = {0.f, 0.f, 0.f, 0.f, 0.f};
    #pragma unroll 4
    for (int k = 0; k < 64; ++k) {
        const float wA = W_om1[k * ODDC + lane];
        const float wB = W_om1[(64 + k) * ODDC + lane];
        #pragma unroll
        for (int mi = 0; mi < PW; ++mi) {
            om[mi] = fmaf(bc(ie [mi], k), wA, om[mi]);
            om[mi] = fmaf(bc(ieo[mi], k), wB, om[mi]);
        }
    }
    float acc_o = 0.f;
    #pragma unroll
    for (int mi = 0; mi < PW; ++mi) acc_o += sg(og[mi]) * tanhf(om[mi]);

    // ---- block reduction across the 4 waves
    __shared__ float red_e[4][64];
    __shared__ float red_o[4][64];
    red_e[wave][lane] = acc_e;
    red_o[wave][lane] = acc_o;
    __syncthreads();

    if (threadIdx.x < 64) {
        const float se = red_e[0][lane] + red_e[1][lane] + red_e[2][lane] + red_e[3][lane];
        const float so = red_o[0][lane] + red_o[1][lane] + red_o[2][lane] + red_o[3][lane];
        out[(long)n * EVENC + lane] = ei + se;
        out[(long)NN * EVENC + (long)n * ODDC + lane] = oi + so;
    }
}

extern "C" void kernel_launch(void* const* d_in, const int* in_sizes, int n_in,
                              void* d_out, int out_size, void* d_ws, size_t ws_size,
                              hipStream_t stream) {
    const float* even_node = (const float*)d_in[0];
    const float* odd_node  = (const float*)d_in[1];
    const float* nbr_fea   = (const float*)d_in[2];
    const int*   nbr_idx   = (const int*)d_in[3];
    const float* W_em1 = (const float*)d_in[4];
    const float* b_em1 = (const float*)d_in[5];
    const float* W_eg  = (const float*)d_in[6];
    const float* b_eg  = (const float*)d_in[7];
    const float* W_em2 = (const float*)d_in[8];
    const float* b_em2 = (const float*)d_in[9];
    const float* W_pej = (const float*)d_in[10];
    const float* b_pej = (const float*)d_in[11];
    const float* W_pei = (const float*)d_in[12];
    const float* b_pei = (const float*)d_in[13];
    const float* W_om1 = (const float*)d_in[14];
    const float* W_ogh = (const float*)d_in[15];
    const float* b_ogh = (const float*)d_in[16];
    const float* W_og  = (const float*)d_in[17];
    const float* b_og  = (const float*)d_in[18];

    eoconv_kernel<<<dim3(NN), dim3(256), 0, stream>>>(
        even_node, odd_node, nbr_fea, nbr_idx,
        W_em1, b_em1, W_eg, b_eg, W_em2, b_em2,
        W_pej, b_pej, W_pei, b_pei, W_om1,
        W_ogh, b_ogh, W_og, b_og,
        (float*)d_out);
}

// Round 3
// 2439.813 us; speedup vs baseline: 1.5765x; 1.5765x over previous
//
#include <hip/hip_runtime.h>

// EvenOddConvLayer MFMA version. N=50000, M=20, EVEN=ODD=64, EDGE=32, CAT=224.
// Block = 8 nodes = 160 pairs (10 Mtiles x 16 rows). 4 waves; wave w owns
// output-column stripe [16w,16w+16) in every GEMM. bf16 MFMA 16x16x32,
// fp32 accumulate. Weights prepacked (fp32->bf16, B-fragment order) into a
// __device__ buffer by a small kernel each launch.

#define NN    50000
#define GN    8
#define PAIRS 160
#define MT    10
#define CSTR  232   // cat row stride (shorts): 464B, 16B-aligned, 2-way banks
#define ESTR  72    // eh/oh/oj stride: 144B
#define ISTR  136   // io stride: 272B

typedef __attribute__((ext_vector_type(8))) short  short8;
typedef __attribute__((ext_vector_type(4))) float  floatx4;

__device__ unsigned char g_wbuf[114688];

#define OFF_EM1 0
#define OFF_OGH 28672
#define OFF_EG  57344
#define OFF_EM2 65536
#define OFF_OG  73728
#define OFF_PEJ 81920
#define OFF_PEI 90112
#define OFF_OM1 98304

__device__ __forceinline__ unsigned short f2b(float x) {        // RNE fp32->bf16
    unsigned u = __float_as_uint(x);
    return (unsigned short)((u + 0x7fffu + ((u >> 16) & 1u)) >> 16);
}
__device__ __forceinline__ float b2f(unsigned short s) {
    return __uint_as_float(((unsigned)s) << 16);
}
__device__ __forceinline__ float sp(float x) { return fmaxf(x, 0.f) + log1pf(expf(-fabsf(x))); }
__device__ __forceinline__ float sg(float x) { return 1.f / (1.f + expf(-x)); }

__device__ __forceinline__ floatx4 mfma16(short8 a, short8 b, floatx4 c) {
    return __builtin_amdgcn_mfma_f32_16x16x32_bf16(a, b, c, 0, 0, 0);
}
__device__ __forceinline__ short8 wfrag(int base, int s, int t, int l) {
    return *(const short8*)(g_wbuf + base + ((size_t)((s * 4 + t) * 64 + l)) * 16);
}

// ---------------- weight prepack: fragment order B[k=quad*8+j][n=lane&15] ----
__global__ __launch_bounds__(256) void prepack(
    const float* __restrict__ W_em1, const float* __restrict__ W_ogh,
    const float* __restrict__ W_eg,  const float* __restrict__ W_em2,
    const float* __restrict__ W_og,  const float* __restrict__ W_pej,
    const float* __restrict__ W_pei, const float* __restrict__ W_om1)
{
    int tid = blockIdx.x * 256 + threadIdx.x;
    int gid = tid >> 6, l = tid & 63;
    const float* W; int base, gl;
    if      (gid < 28) { W = W_em1; base = OFF_EM1; gl = gid;      }
    else if (gid < 56) { W = W_ogh; base = OFF_OGH; gl = gid - 28; }
    else if (gid < 64) { W = W_eg;  base = OFF_EG;  gl = gid - 56; }
    else if (gid < 72) { W = W_em2; base = OFF_EM2; gl = gid - 64; }
    else if (gid < 80) { W = W_og;  base = OFF_OG;  gl = gid - 72; }
    else if (gid < 88) { W = W_pej; base = OFF_PEJ; gl = gid - 80; }
    else if (gid < 96) { W = W_pei; base = OFF_PEI; gl = gid - 88; }
    else               { W = W_om1; base = OFF_OM1; gl = gid - 96; }
    int s = gl >> 2, t = gl & 3;
    int k0 = s * 32 + (l >> 4) * 8;
    int n  = t * 16 + (l & 15);
    short8 pk;
    #pragma unroll
    for (int j = 0; j < 8; ++j) pk[j] = (short)f2b(W[(size_t)(k0 + j) * 64 + n]);
    *(short8*)(g_wbuf + base + ((size_t)((s * 4 + t) * 64 + l)) * 16) = pk;
}

// ---------------- main kernel ------------------------------------------------
__global__ __launch_bounds__(256, 1) void eoconv_mfma(
    const float* __restrict__ even_node, const float* __restrict__ odd_node,
    const float* __restrict__ nbr_fea,   const int* __restrict__ nbr_idx,
    const float* __restrict__ b_em1, const float* __restrict__ b_eg,
    const float* __restrict__ b_em2, const float* __restrict__ b_pej,
    const float* __restrict__ b_pei, const float* __restrict__ b_ogh,
    const float* __restrict__ b_og,  float* __restrict__ out)
{
    extern __shared__ char smem[];
    short* sh_cat = (short*)smem;                  // [160][CSTR] bf16
    short* sh_io  = (short*)smem;                  // [160][ISTR] bf16 (reuse)
    float* red_e  = (float*)smem;                  // [160][64]  f32 (reuse)
    short* sh_eh  = (short*)(smem + 74240);        // [160][ESTR]
    float* red_o  = (float*)(smem + 74240);        // [160][64] over eh+oh
    short* sh_oh  = (short*)(smem + 97280);        // [160][ESTR]
    short* sh_oj  = (short*)(smem + 120320);       // [160][ESTR]
    float* sh_oi  = (float*)(smem + 143360);       // [8][64]

    const int w  = threadIdx.x >> 6;
    const int l  = threadIdx.x & 63;
    const int n0 = blockIdx.x * GN;

    // ---- stage cat / oj / oi
    for (int i = 0; i < 40; ++i) {
        int  r = w * 40 + i;
        int  g = r / 20, m = r - g * 20;
        int  n = n0 + g;
        long p = (long)n0 * 20 + r;                // = n*20+m
        int  j = nbr_idx[p];
        float eif = even_node[(long)n * 64 + l];
        float oif = odd_node [(long)n * 64 + l];
        float ejf = even_node[(long)j * 64 + l];
        float ojf = odd_node [(long)j * 64 + l];
        sh_cat[r * CSTR + l]        = (short)f2b(eif);
        sh_cat[r * CSTR + 64 + l]   = (short)f2b(ejf);
        if (l < 32) sh_cat[r * CSTR + 128 + l] = (short)f2b(nbr_fea[p * 32 + l]);
        sh_cat[r * CSTR + 160 + l]  = (short)f2b(oif * ojf);
        sh_oj[r * ESTR + l]         = (short)f2b(ojf);
        if (m == 0) sh_oi[g * 64 + l] = oif;
    }
    __syncthreads();

    const int col = w * 16 + (l & 15);
    const int q4  = (l >> 4) * 4;
    const float be1 = b_em1[col], bgh = b_ogh[col], bpi = b_pei[col], bpj = b_pej[col];
    const float beg = b_eg[col],  bm2 = b_em2[col], bog = b_og[col];

    // ---- GEMM1: cat@{W_em1,W_ogh}; cat[:,0:64]@W_pei; cat[:,64:128]@W_pej
    floatx4 C1[MT], Cg[MT], Cpi[MT], Cpj[MT];
    const floatx4 z4 = {0.f, 0.f, 0.f, 0.f};
    #pragma unroll
    for (int t = 0; t < MT; ++t) { C1[t] = z4; Cg[t] = z4; Cpi[t] = z4; Cpj[t] = z4; }

    #pragma unroll
    for (int ks = 0; ks < 7; ++ks) {
        short8 B1 = wfrag(OFF_EM1, ks, w, l);
        short8 Bg = wfrag(OFF_OGH, ks, w, l);
        short8 Bx = B1;
        if (ks < 2)      Bx = wfrag(OFF_PEI, ks, w, l);
        else if (ks < 4) Bx = wfrag(OFF_PEJ, ks - 2, w, l);
        const int ko = ks * 32 + (l >> 4) * 8;
        #pragma unroll
        for (int t = 0; t < MT; ++t) {
            short8 A = *(const short8*)&sh_cat[(t * 16 + (l & 15)) * CSTR + ko];
            C1[t] = mfma16(A, B1, C1[t]);
            Cg[t] = mfma16(A, Bg, Cg[t]);
            if (ks < 2)      Cpi[t] = mfma16(A, Bx, Cpi[t]);
            else if (ks < 4) Cpj[t] = mfma16(A, Bx, Cpj[t]);
        }
    }

    // ---- epilogue 1: activations, eh/oh to LDS, pointwise ie/ieo (regs)
    unsigned pk[MT][4];
    #pragma unroll
    for (int t = 0; t < MT; ++t) {
        #pragma unroll
        for (int rg = 0; rg < 4; ++rg) {
            int row = t * 16 + q4 + rg;
            sh_eh[row * ESTR + col] = (short)f2b(sp(C1[t][rg] + be1));
            sh_oh[row * ESTR + col] = (short)f2b(sp(Cg[t][rg] + bgh));
            float pei = Cpi[t][rg] + bpi;
            float pj  = Cpj[t][rg] + bpj;
            int   gg  = row / 20;
            float oi  = sh_oi[gg * 64 + col];
            float oj  = b2f((unsigned short)sh_oj[row * ESTR + col]);
            pk[t][rg] = (unsigned)f2b(oi * pj) | ((unsigned)f2b(pei * oj) << 16);
        }
    }
    __syncthreads();                               // all cat reads complete

    #pragma unroll
    for (int t = 0; t < MT; ++t) {
        #pragma unroll
        for (int rg = 0; rg < 4; ++rg) {
            int row = t * 16 + q4 + rg;
            sh_io[row * ISTR + col]      = (short)(pk[t][rg] & 0xffffu);
            sh_io[row * ISTR + 64 + col] = (short)(pk[t][rg] >> 16);
        }
    }
    __syncthreads();                               // io visible

    // ---- GEMM2: eh@{W_eg,W_em2}, oh@W_og ; GEMM3: io@W_om1 (K=128)
    floatx4 Gg[MT], Gm[MT], Go[MT], Gt[MT];
    #pragma unroll
    for (int t = 0; t < MT; ++t) { Gg[t] = z4; Gm[t] = z4; Go[t] = z4; Gt[t] = z4; }

    #pragma unroll
    for (int ks = 0; ks < 2; ++ks) {
        short8 Beg = wfrag(OFF_EG,  ks, w, l);
        short8 Bm2 = wfrag(OFF_EM2, ks, w, l);
        short8 Bog = wfrag(OFF_OG,  ks, w, l);
        const int ko = ks * 32 + (l >> 4) * 8;
        #pragma unroll
        for (int t = 0; t < MT; ++t) {
            short8 Ae = *(const short8*)&sh_eh[(t * 16 + (l & 15)) * ESTR + ko];
            short8 Ao = *(const short8*)&sh_oh[(t * 16 + (l & 15)) * ESTR + ko];
            Gg[t] = mfma16(Ae, Beg, Gg[t]);
            Gm[t] = mfma16(Ae, Bm2, Gm[t]);
            Go[t] = mfma16(Ao, Bog, Go[t]);
        }
    }
    #pragma unroll
    for (int ks = 0; ks < 4; ++ks) {
        short8 Bo = wfrag(OFF_OM1, ks, w, l);
        const int ko = ks * 32 + (l >> 4) * 8;
        #pragma unroll
        for (int t = 0; t < MT; ++t) {
            short8 Ai = *(const short8*)&sh_io[(t * 16 + (l & 15)) * ISTR + ko];
            Gt[t] = mfma16(Ai, Bo, Gt[t]);
        }
    }
    __syncthreads();                               // eh/oh/io reads done

    // ---- epilogue 2: gates, per-pair contributions to LDS
    #pragma unroll
    for (int t = 0; t < MT; ++t) {
        #pragma unroll
        for (int rg = 0; rg < 4; ++rg) {
            int row = t * 16 + q4 + rg;
            red_e[row * 64 + col] = sg(Gg[t][rg] + beg) * sp(Gm[t][rg] + bm2);
            red_o[row * 64 + col] = sg(Go[t][rg] + bog) * tanhf(Gt[t][rg]);
        }
    }
    __syncthreads();

    // ---- reduce 20 pairs per node, add residual, store
    {
        int q = l >> 4;
        #pragma unroll
        for (int t2 = 0; t2 < 2; ++t2) {
            int gg = q + 4 * t2;
            int n  = n0 + gg;
            float se = 0.f, so = 0.f;
            #pragma unroll 4
            for (int i = 0; i < 20; ++i) {
                se += red_e[(gg * 20 + i) * 64 + col];
                so += red_o[(gg * 20 + i) * 64 + col];
            }
            out[(long)n * 64 + col]                  = even_node[(long)n * 64 + col] + se;
            out[(long)NN * 64 + (long)n * 64 + col]  = odd_node [(long)n * 64 + col] + so;
        }
    }
}

extern "C" void kernel_launch(void* const* d_in, const int* in_sizes, int n_in,
                              void* d_out, int out_size, void* d_ws, size_t ws_size,
                              hipStream_t stream) {
    const float* even_node = (const float*)d_in[0];
    const float* odd_node  = (const float*)d_in[1];
    const float* nbr_fea   = (const float*)d_in[2];
    const int*   nbr_idx   = (const int*)d_in[3];
    const float* W_em1 = (const float*)d_in[4];
    const float* b_em1 = (const float*)d_in[5];
    const float* W_eg  = (const float*)d_in[6];
    const float* b_eg  = (const float*)d_in[7];
    const float* W_em2 = (const float*)d_in[8];
    const float* b_em2 = (const float*)d_in[9];
    const float* W_pej = (const float*)d_in[10];
    const float* b_pej = (const float*)d_in[11];
    const float* W_pei = (const float*)d_in[12];
    const float* b_pei = (const float*)d_in[13];
    const float* W_om1 = (const float*)d_in[14];
    const float* W_ogh = (const float*)d_in[15];
    const float* b_ogh = (const float*)d_in[16];
    const float* W_og  = (const float*)d_in[17];
    const float* b_og  = (const float*)d_in[18];

    static int s_attr_done = 0;                    // host-side config, idempotent
    if (!s_attr_done) {
        hipFuncSetAttribute((const void*)eoconv_mfma,
                            hipFuncAttributeMaxDynamicSharedMemorySize, 145408);
        s_attr_done = 1;
    }

    prepack<<<dim3(28), dim3(256), 0, stream>>>(W_em1, W_ogh, W_eg, W_em2,
                                                W_og, W_pej, W_pei, W_om1);
    eoconv_mfma<<<dim3(NN / GN), dim3(256), 145408, stream>>>(
        even_node, odd_node, nbr_fea, nbr_idx,
        b_em1, b_eg, b_em2, b_pej, b_pei, b_ogh, b_og,
        (float*)d_out);
}

// Round 5
// 957.063 us; speedup vs baseline: 4.0188x; 2.5493x over previous
//
#include <hip/hip_runtime.h>

// EvenOddConvLayer MFMA v3. N=50000, M=20, EVEN=ODD=64, EDGE=32, CAT=224.
// Round-3 structure (verified correct) with ONLY the occupancy fix:
// GN 8->4 (80 pairs, 5 Mtiles), LDS 72.7KB -> 2 blocks/CU, fast lane-local
// transcendentals. 4 waves; wave w = col stripe [16w,16w+16) in every GEMM;
// wave w stages + reduces node w. Weights prepacked fp32->bf16 in B-fragment
// order (layout verified round 3).

#define NN    50000
#define GN    4
#define MT    5
#define CSTR  232      // cat row stride (shorts): [ei 0 | ej 64 | nbr 128 | cross 160]
#define ESTR  72       // eh / oh / oj row stride (shorts)
#define IOSTR 136      // io row stride (shorts): [ie 0 | ieo 64]

#define LDS_A   0      // cat(37120) -> io(21760) -> red_e(20480)
#define LDS_EH  37120  // eh (11520); red_o(20480) overlays eh+oh
#define LDS_OH  48640  // oh (11520)
#define LDS_OJ  60160  // oj (11520)
#define LDS_OI  71680  // oi 4x64 f32 (1024)
#define LDS_SZ  72704

typedef __attribute__((ext_vector_type(8))) short  short8;
typedef __attribute__((ext_vector_type(4))) float  floatx4;

__device__ unsigned char g_wbuf[114688];

#define OFF_EM1 0
#define OFF_OGH 28672
#define OFF_EG  57344
#define OFF_EM2 65536
#define OFF_OG  73728
#define OFF_PEJ 81920
#define OFF_PEI 90112
#define OFF_OM1 98304

__device__ __forceinline__ unsigned short f2b(float x) {        // RNE fp32->bf16
    unsigned u = __float_as_uint(x);
    return (unsigned short)((u + 0x7fffu + ((u >> 16) & 1u)) >> 16);
}
__device__ __forceinline__ float b2f(unsigned short s) {
    return __uint_as_float(((unsigned)s) << 16);
}
__device__ __forceinline__ float spf(float x) {                 // softplus, fast
    return fmaxf(x, 0.f) + __logf(1.f + __expf(-fabsf(x)));
}
__device__ __forceinline__ float sgf(float x) {                 // sigmoid, fast
    return __builtin_amdgcn_rcpf(1.f + __expf(-x));
}
__device__ __forceinline__ float thf(float x) {                 // tanh, fast
    float e = __expf(-2.f * fabsf(x));
    float t = (1.f - e) * __builtin_amdgcn_rcpf(1.f + e);
    return __builtin_copysignf(t, x);
}
__device__ __forceinline__ floatx4 mfma16(short8 a, short8 b, floatx4 c) {
    return __builtin_amdgcn_mfma_f32_16x16x32_bf16(a, b, c, 0, 0, 0);
}
__device__ __forceinline__ short8 wfrag(int base, int s, int t, int l) {
    return *(const short8*)(g_wbuf + base + ((size_t)((s * 4 + t) * 64 + l)) * 16);
}

// ---------------- weight prepack (identical to round 3, verified) -----------
__global__ __launch_bounds__(256) void prepack(
    const float* __restrict__ W_em1, const float* __restrict__ W_ogh,
    const float* __restrict__ W_eg,  const float* __restrict__ W_em2,
    const float* __restrict__ W_og,  const float* __restrict__ W_pej,
    const float* __restrict__ W_pei, const float* __restrict__ W_om1)
{
    int tid = blockIdx.x * 256 + threadIdx.x;
    int gid = tid >> 6, l = tid & 63;
    const float* W; int base, gl;
    if      (gid < 28) { W = W_em1; base = OFF_EM1; gl = gid;      }
    else if (gid < 56) { W = W_ogh; base = OFF_OGH; gl = gid - 28; }
    else if (gid < 64) { W = W_eg;  base = OFF_EG;  gl = gid - 56; }
    else if (gid < 72) { W = W_em2; base = OFF_EM2; gl = gid - 64; }
    else if (gid < 80) { W = W_og;  base = OFF_OG;  gl = gid - 72; }
    else if (gid < 88) { W = W_pej; base = OFF_PEJ; gl = gid - 80; }
    else if (gid < 96) { W = W_pei; base = OFF_PEI; gl = gid - 88; }
    else               { W = W_om1; base = OFF_OM1; gl = gid - 96; }
    int s = gl >> 2, t = gl & 3;
    int k0 = s * 32 + (l >> 4) * 8;
    int n  = t * 16 + (l & 15);
    short8 pk;
    #pragma unroll
    for (int j = 0; j < 8; ++j) pk[j] = (short)f2b(W[(size_t)(k0 + j) * 64 + n]);
    *(short8*)(g_wbuf + base + ((size_t)((s * 4 + t) * 64 + l)) * 16) = pk;
}

// ---------------- main kernel ------------------------------------------------
__global__ __launch_bounds__(256, 2) void eoconv_mfma(
    const float* __restrict__ even_node, const float* __restrict__ odd_node,
    const float* __restrict__ nbr_fea,   const int* __restrict__ nbr_idx,
    const float* __restrict__ b_em1, const float* __restrict__ b_eg,
    const float* __restrict__ b_em2, const float* __restrict__ b_pej,
    const float* __restrict__ b_pei, const float* __restrict__ b_ogh,
    const float* __restrict__ b_og,  float* __restrict__ out)
{
    extern __shared__ char smem[];
    short* sh_cat = (short*)(smem + LDS_A);
    short* sh_io  = (short*)(smem + LDS_A);
    float* red_e  = (float*)(smem + LDS_A);
    short* sh_eh  = (short*)(smem + LDS_EH);
    float* red_o  = (float*)(smem + LDS_EH);
    short* sh_oh  = (short*)(smem + LDS_OH);
    short* sh_oj  = (short*)(smem + LDS_OJ);
    float* sh_oi  = (float*)(smem + LDS_OI);

    const int w  = threadIdx.x >> 6;
    const int l  = threadIdx.x & 63;
    const int n0 = blockIdx.x * GN;

    // ---- stage node w's 20 pair rows (round-3 pattern)
    const float eif = even_node[(long)(n0 + w) * 64 + l];
    const float oif = odd_node [(long)(n0 + w) * 64 + l];
    sh_oi[w * 64 + l] = oif;
    #pragma unroll 4
    for (int i = 0; i < 20; ++i) {
        const int  r = w * 20 + i;
        const long p = (long)n0 * 20 + r;          // = (n0+w)*20 + i
        const int  j = nbr_idx[p];
        const float ejf = even_node[(long)j * 64 + l];
        const float ojf = odd_node [(long)j * 64 + l];
        sh_cat[r * CSTR + l]        = (short)f2b(eif);
        sh_cat[r * CSTR + 64 + l]   = (short)f2b(ejf);
        if (l < 32) sh_cat[r * CSTR + 128 + l] = (short)f2b(nbr_fea[p * 32 + l]);
        sh_cat[r * CSTR + 160 + l]  = (short)f2b(oif * ojf);
        sh_oj[r * ESTR + l]         = (short)f2b(ojf);
    }
    __syncthreads();

    const int col = w * 16 + (l & 15);
    const int q8  = (l >> 4) * 8;
    const int q4  = (l >> 4) * 4;
    const float be1 = b_em1[col], bgh = b_ogh[col], bpi = b_pei[col], bpj = b_pej[col];
    const floatx4 z4 = {0.f, 0.f, 0.f, 0.f};

    // ---- GEMM1: cat@{W_em1,W_ogh}; cat[:,0:64]@W_pei; cat[:,64:128]@W_pej
    floatx4 C1[MT], Cg[MT], Cpi[MT], Cpj[MT];
    #pragma unroll
    for (int t = 0; t < MT; ++t) { C1[t] = z4; Cg[t] = z4; Cpi[t] = z4; Cpj[t] = z4; }
    #pragma unroll
    for (int ks = 0; ks < 7; ++ks) {
        short8 B1 = wfrag(OFF_EM1, ks, w, l);
        short8 Bg = wfrag(OFF_OGH, ks, w, l);
        short8 Bx = B1;
        if (ks < 2)      Bx = wfrag(OFF_PEI, ks, w, l);
        else if (ks < 4) Bx = wfrag(OFF_PEJ, ks - 2, w, l);
        const int ko = ks * 32 + q8;
        #pragma unroll
        for (int t = 0; t < MT; ++t) {
            short8 A = *(const short8*)&sh_cat[(t * 16 + (l & 15)) * CSTR + ko];
            C1[t] = mfma16(A, B1, C1[t]);
            Cg[t] = mfma16(A, Bg, Cg[t]);
            if (ks < 2)      Cpi[t] = mfma16(A, Bx, Cpi[t]);
            else if (ks < 4) Cpj[t] = mfma16(A, Bx, Cpj[t]);
        }
    }

    // ---- epilogue 1: eh/oh to LDS, ie/ieo packed in regs
    unsigned pk[MT][4];
    #pragma unroll
    for (int t = 0; t < MT; ++t) {
        #pragma unroll
        for (int rg = 0; rg < 4; ++rg) {
            const int row = t * 16 + q4 + rg;
            sh_eh[row * ESTR + col] = (short)f2b(spf(C1[t][rg] + be1));
            sh_oh[row * ESTR + col] = (short)f2b(spf(Cg[t][rg] + bgh));
            const float pei = Cpi[t][rg] + bpi;
            const float pj  = Cpj[t][rg] + bpj;
            const int   g   = row / 20;
            const float oi  = sh_oi[g * 64 + col];
            const float oj  = b2f((unsigned short)sh_oj[row * ESTR + col]);
            pk[t][rg] = (unsigned)f2b(oi * pj) | ((unsigned)f2b(pei * oj) << 16);
        }
    }
    __syncthreads();                               // all cat reads complete

    #pragma unroll
    for (int t = 0; t < MT; ++t) {
        #pragma unroll
        for (int rg = 0; rg < 4; ++rg) {
            const int row = t * 16 + q4 + rg;
            sh_io[row * IOSTR + col]      = (short)(pk[t][rg] & 0xffffu);
            sh_io[row * IOSTR + 64 + col] = (short)(pk[t][rg] >> 16);
        }
    }

    // ---- GEMM2: eh@{W_eg,W_em2}, oh@W_og (K=64)
    floatx4 Gg[MT], Gm[MT], Go[MT];
    #pragma unroll
    for (int t = 0; t < MT; ++t) { Gg[t] = z4; Gm[t] = z4; Go[t] = z4; }
    #pragma unroll
    for (int ks = 0; ks < 2; ++ks) {
        short8 Beg = wfrag(OFF_EG,  ks, w, l);
        short8 Bm2 = wfrag(OFF_EM2, ks, w, l);
        short8 Bog = wfrag(OFF_OG,  ks, w, l);
        const int ko = ks * 32 + q8;
        #pragma unroll
        for (int t = 0; t < MT; ++t) {
            short8 Ae = *(const short8*)&sh_eh[(t * 16 + (l & 15)) * ESTR + ko];
            short8 Ao = *(const short8*)&sh_oh[(t * 16 + (l & 15)) * ESTR + ko];
            Gg[t] = mfma16(Ae, Beg, Gg[t]);
            Gm[t] = mfma16(Ae, Bm2, Gm[t]);
            Go[t] = mfma16(Ao, Bog, Go[t]);
        }
    }
    __syncthreads();                               // io visible

    // ---- GEMM3: [ie|ieo] @ W_om1 (K=128)
    floatx4 Gt[MT];
    #pragma unroll
    for (int t = 0; t < MT; ++t) Gt[t] = z4;
    #pragma unroll
    for (int ks = 0; ks < 4; ++ks) {
        short8 Bo = wfrag(OFF_OM1, ks, w, l);
        const int ko = ks * 32 + q8;
        #pragma unroll
        for (int t = 0; t < MT; ++t) {
            short8 Ai = *(const short8*)&sh_io[(t * 16 + (l & 15)) * IOSTR + ko];
            Gt[t] = mfma16(Ai, Bo, Gt[t]);
        }
    }
    __syncthreads();                               // io/eh/oh reads done (red overlays)

    // ---- epilogue 2: gates, per-pair contributions
    {
        const float beg = b_eg[col], bm2 = b_em2[col], bog = b_og[col];
        #pragma unroll
        for (int t = 0; t < MT; ++t) {
            #pragma unroll
            for (int rg = 0; rg < 4; ++rg) {
                const int row = t * 16 + q4 + rg;
                red_e[row * 64 + col] = sgf(Gg[t][rg] + beg) * spf(Gm[t][rg] + bm2);
                red_o[row * 64 + col] = sgf(Go[t][rg] + bog) * thf(Gt[t][rg]);
            }
        }
    }
    __syncthreads();

    // ---- reduce 20 pairs (wave w -> node w), residual, store
    {
        float se = 0.f, so = 0.f;
        #pragma unroll 4
        for (int i = 0; i < 20; ++i) {
            se += red_e[(w * 20 + i) * 64 + l];
            so += red_o[(w * 20 + i) * 64 + l];
        }
        const long nb = (long)(n0 + w) * 64 + l;
        out[nb]                 = eif + se;
        out[(long)NN * 64 + nb] = oif + so;
    }
}

extern "C" void kernel_launch(void* const* d_in, const int* in_sizes, int n_in,
                              void* d_out, int out_size, void* d_ws, size_t ws_size,
                              hipStream_t stream) {
    const float* even_node = (const float*)d_in[0];
    const float* odd_node  = (const float*)d_in[1];
    const float* nbr_fea   = (const float*)d_in[2];
    const int*   nbr_idx   = (const int*)d_in[3];
    const float* W_em1 = (const float*)d_in[4];
    const float* b_em1 = (const float*)d_in[5];
    const float* W_eg  = (const float*)d_in[6];
    const float* b_eg  = (const float*)d_in[7];
    const float* W_em2 = (const float*)d_in[8];
    const float* b_em2 = (const float*)d_in[9];
    const float* W_pej = (const float*)d_in[10];
    const float* b_pej = (const float*)d_in[11];
    const float* W_pei = (const float*)d_in[12];
    const float* b_pei = (const float*)d_in[13];
    const float* W_om1 = (const float*)d_in[14];
    const float* W_ogh = (const float*)d_in[15];
    const float* b_ogh = (const float*)d_in[16];
    const float* W_og  = (const float*)d_in[17];
    const float* b_og  = (const float*)d_in[18];

    static int s_attr_done = 0;                     // host-side config, idempotent
    if (!s_attr_done) {
        hipFuncSetAttribute((const void*)eoconv_mfma,
                            hipFuncAttributeMaxDynamicSharedMemorySize, LDS_SZ);
        s_attr_done = 1;
    }

    prepack<<<dim3(28), dim3(256), 0, stream>>>(W_em1, W_ogh, W_eg, W_em2,
                                                W_og, W_pej, W_pei, W_om1);
    eoconv_mfma<<<dim3(NN / GN), dim3(256), LDS_SZ, stream>>>(
        even_node, odd_node, nbr_fea, nbr_idx,
        b_em1, b_eg, b_em2, b_pej, b_pei, b_ogh, b_og,
        (float*)d_out);
}